// Round 6
// baseline (122.357 us; speedup 1.0000x reference)
//
#include <hip/hip_runtime.h>
#include <math.h>
#include <stdint.h>

// Match numpy float32 semantics exactly in branchy geometry (no FMA contraction).
#pragma clang fp contract(off)

struct WS {
  double sums[8];                  // 0 cls, 1 gl_i, 2 oob_i, 3 gl_r, 4 oob_r
  unsigned long long packed[128];  // (dd2_bits<<32)|idx per (a*64+k)
  unsigned cntpub[2];              // published positive counts
  unsigned done2;                  // k_post completion counter
};

// ============ k_init: zero accumulators ============
__global__ void k_init(WS* ws) {
  int t = threadIdx.x;
  if (t < 8) ws->sums[t] = 0.0;
  if (t < 128) ws->packed[t] = ~0ULL;
  if (t == 0) { ws->done2 = 0u; ws->cntpub[0] = 0u; ws->cntpub[1] = 0u; }
}

// ============ k_main: fused GT-prep + point-centric argmin + cls lse ============
// One block = 256 consecutive points. Each block redundantly preps all K GTs
// (cheap, L2-hot) — removes the separate k_pre kernel and its serial binary
// search. Each point's xy is read ONCE per stage; per-GT block min via wave
// shfl butterfly + LDS cross-wave combine + one atomicMin per (stage,gt).
// dd^2 (no sqrt) and *inv instead of /: monotone => identical winner set
// (up to 1-ulp tie collisions, measure-zero).
__global__ void __launch_bounds__(256) k_main(const float* __restrict__ rpi,
                                              const float* __restrict__ rpr,
                                              const float* __restrict__ cls,
                                              const float* __restrict__ stridev,
                                              const float* __restrict__ gob,
                                              int N, int K, WS* ws) {
  __shared__ float gcx[64], gcy[64], giw[64], gih[64];
  __shared__ int glv[64];
  __shared__ unsigned long long wmin[4][128];
  __shared__ double sd[256];
  int t = threadIdx.x;
  int i = blockIdx.x * 256 + t;

  // --- GT prep (threads 0..K-1) ---
  if (t < K) {
    const float* g = gob + t * 8;
    float x0 = g[0], x1 = g[2], x2 = g[4], x3 = g[6];
    float y0 = g[1], y1 = g[3], y2 = g[5], y3 = g[7];
    float xmin = fminf(fminf(x0, x1), fminf(x2, x3));
    float xmax = fmaxf(fmaxf(x0, x1), fmaxf(x2, x3));
    float ymin = fminf(fminf(y0, y1), fminf(y2, y3));
    float ymax = fmaxf(fmaxf(y0, y1), fmaxf(y2, y3));
    float w = fmaxf(xmax - xmin, 1e-6f);
    float h = fmaxf(ymax - ymin, 1e-6f);
    gcx[t] = (xmin + xmax) * 0.5f;
    gcy[t] = (ymin + ymax) * 0.5f;
    giw[t] = 1.f / w;
    gih[t] = 1.f / h;
    // lvl clamp bounds: stridev is sorted ascending by construction
    int lmin = (int)log2f(stridev[0]);
    int lmax = (int)log2f(stridev[N - 1]);
    int gl = (int)((log2f(w * 0.25f) + log2f(h * 0.25f)) * 0.5f);  // trunc (positive)
    gl = gl < lmin ? lmin : (gl > lmax ? lmax : gl);
    glv[t] = gl;
  }
  // --- init per-wave minima ---
  unsigned long long* wf = &wmin[0][0];
  wf[t] = ~0ULL;
  wf[t + 256] = ~0ULL;

  // --- per-thread point data (single touch) ---
  bool act = (i < N);
  int L = -1;
  float xi = 0.f, yi = 0.f, xr = 0.f, yr = 0.f;
  if (act) {
    L = (int)log2f(stridev[i]);
    const float2 pi = *(const float2*)(rpi + (size_t)i * 18 + 8);
    const float2 pr = *(const float2*)(rpr + (size_t)i * 18 + 8);
    xi = pi.x; yi = pi.y; xr = pr.x; yr = pr.y;
  }
  __syncthreads();

  int lane = t & 63, wv = t >> 6;
  for (int k = 0; k < K; k++) {
    bool m = act && (glv[k] == L);
    if (__ballot(m)) {  // wave-uniform skip: most GTs are at another level
      unsigned long long p0 = ~0ULL, p1 = ~0ULL;
      if (m) {
        float cx = gcx[k], cy = gcy[k], iw = giw[k], ih = gih[k];
        float dx = (xi - cx) * iw, dy = (yi - cy) * ih;
        float d2 = dx * dx + dy * dy;
        p0 = ((unsigned long long)__float_as_uint(d2) << 32) | (unsigned)i;
        dx = (xr - cx) * iw; dy = (yr - cy) * ih;
        d2 = dx * dx + dy * dy;
        p1 = ((unsigned long long)__float_as_uint(d2) << 32) | (unsigned)i;
      }
      #pragma unroll
      for (int off = 32; off > 0; off >>= 1) {
        unsigned long long o0 = __shfl_xor(p0, off);
        unsigned long long o1 = __shfl_xor(p1, off);
        if (o0 < p0) p0 = o0;
        if (o1 < p1) p1 = o1;
      }
      if (lane == 0) { wmin[wv][k] = p0; wmin[wv][64 + k] = p1; }
    }
  }
  __syncthreads();
  if (t < 128) {
    unsigned long long v = wmin[0][t];
    if (wmin[1][t] < v) v = wmin[1][t];
    if (wmin[2][t] < v) v = wmin[2][t];
    if (wmin[3][t] < v) v = wmin[3][t];
    if (v != ~0ULL) atomicMin(&ws->packed[t], v);
  }

  // --- cls base loss: sum_i (lse_i - x_i[0]) ---
  double v = 0.0;
  if (act) {
    const float4* r = (const float4*)(cls + (size_t)i * 16);
    float4 q0 = r[0], q1 = r[1], q2 = r[2], q3 = r[3];
    float x[16] = {q0.x, q0.y, q0.z, q0.w, q1.x, q1.y, q1.z, q1.w,
                   q2.x, q2.y, q2.z, q2.w, q3.x, q3.y, q3.z, q3.w};
    float m = x[0];
    for (int j = 1; j < 16; j++) m = fmaxf(m, x[j]);
    float ssum = 0.f;
    for (int j = 0; j < 16; j++) ssum += expf(x[j] - m);
    v = (double)(logf(ssum) + m - x[0]);
  }
  sd[t] = v;
  __syncthreads();
  for (int off = 128; off > 0; off >>= 1) {
    if (t < off) sd[t] += sd[t + off];
    __syncthreads();
  }
  if (t == 0) atomicAdd(&ws->sums[0], sd[0]);
}

// ============ wave-parallel geometry helpers (block = 1 wave of 64) ============

__device__ __forceinline__ float shoe(const float* VX, const float* VY, int c) {
  float s = 0.f;
  #pragma unroll
  for (int i = 0; i < 16; i++) {
    if (i < c) {
      int nx = (i + 1 < c) ? ((i + 1 < 16) ? i + 1 : 15) : 0;  // JAX OOB-gather clamp
      s += VX[i] * VY[nx] - VX[nx] * VY[i];
    }
  }
  return 0.5f * fabsf(s);
}

__device__ __forceinline__ int clip_edge(const float* SX, const float* SY, float* DX, float* DY,
                                         int c, float ax, float ay, float bx, float by, int lane) {
  if (lane < 16) { DX[lane] = 0.f; DY[lane] = 0.f; }
  bool f_int = false, f_nxt = false;
  float ix = 0.f, iy = 0.f, nxv = 0.f, nyv = 0.f;
  if (lane < 16 && lane < c) {
    int nxt = (lane + 1 < c) ? lane + 1 : 0;
    if (nxt > 15) nxt = 15;
    float cxv = SX[lane], cyv = SY[lane];
    nxv = SX[nxt]; nyv = SY[nxt];
    float ex = bx - ax, ey = by - ay;
    float s_cur = ex * (cyv - ay) - ey * (cxv - ax);
    float s_nxt = ex * (nyv - ay) - ey * (nxv - ax);
    bool in_cur = s_cur >= 0.f, in_nxt = s_nxt >= 0.f;
    float den = s_cur - s_nxt;
    bool safe = fabsf(den) > 1e-9f;
    float tt = safe ? s_cur / den : 0.f;
    ix = cxv + tt * (nxv - cxv);
    iy = cyv + tt * (nyv - cyv);
    f_int = (in_cur != in_nxt);
    f_nxt = in_nxt;
  }
  unsigned long long bi = __ballot(f_int), bn = __ballot(f_nxt);
  unsigned long long lt = (1ULL << lane) - 1ULL;
  int below = __popcll(bi & lt) + __popcll(bn & lt);
  if (f_int && below < 16) { DX[below] = ix; DY[below] = iy; }
  int posn = below + (f_int ? 1 : 0);
  if (f_nxt && posn < 16) { DX[posn] = nxv; DY[posn] = nyv; }
  __syncthreads();
  return __popcll(bi) + __popcll(bn);
}

template <int NP>
__device__ __forceinline__ int hull_wave(const float* PX, const float* PY, int base,
                                         float* VX, float* VY, float* KEY, int lane) {
  constexpr int TOT = NP * NP;
  unsigned long long B0 = 0, B1 = 0, B2 = 0;
  {
    bool h = false;
    int idx = lane;
    if (idx < TOT) {
      int i = idx / NP, j = idx % NP;
      if (i != j) {
        float pix = PX[base + i], piy = PY[base + i];
        float dx = PX[base + j] - pix, dy = PY[base + j] - piy;
        float m = INFINITY;
        #pragma unroll
        for (int k = 0; k < NP; k++)
          m = fminf(m, dx * (PY[base + k] - piy) - dy * (PX[base + k] - pix));
        h = (m >= -1e-6f);
      }
    }
    B0 = __ballot(h);
  }
  if constexpr (TOT > 64) {
    bool h = false;
    int idx = lane + 64;
    if (idx < TOT) {
      int i = idx / NP, j = idx % NP;
      if (i != j) {
        float pix = PX[base + i], piy = PY[base + i];
        float dx = PX[base + j] - pix, dy = PY[base + j] - piy;
        float m = INFINITY;
        #pragma unroll
        for (int k = 0; k < NP; k++)
          m = fminf(m, dx * (PY[base + k] - piy) - dy * (PX[base + k] - pix));
        h = (m >= -1e-6f);
      }
    }
    B1 = __ballot(h);
  }
  if constexpr (TOT > 128) {
    bool h = false;
    int idx = lane + 128;
    if (idx < TOT) {
      int i = idx / NP, j = idx % NP;
      if (i != j) {
        float pix = PX[base + i], piy = PY[base + i];
        float dx = PX[base + j] - pix, dy = PY[base + j] - piy;
        float m = INFINITY;
        #pragma unroll
        for (int k = 0; k < NP; k++)
          m = fminf(m, dx * (PY[base + k] - piy) - dy * (PX[base + k] - pix));
        h = (m >= -1e-6f);
      }
    }
    B2 = __ballot(h);
  }
  bool hull_i = false;
  if (lane < NP) {
    int s = lane * NP, w = s >> 6, off = s & 63;
    unsigned long long Bw = (w == 0) ? B0 : ((w == 1) ? B1 : B2);
    unsigned long long Bw1 = (w == 0) ? B1 : ((w == 1) ? B2 : 0ULL);
    unsigned long long bits = Bw >> off;
    if (off) bits |= Bw1 << (64 - off);
    hull_i = (bits & ((1ULL << NP) - 1ULL)) != 0ULL;
  }
  unsigned long long hmask = __ballot(hull_i);
  int cnt = __popcll(hmask);
  float cx = 0.f, cy = 0.f;
  #pragma unroll
  for (int k = 0; k < NP; k++)
    if ((hmask >> k) & 1ULL) { cx += PX[base + k]; cy += PY[base + k]; }
  float dn = (float)(cnt > 1 ? cnt : 1);
  cx /= dn; cy /= dn;
  if (lane < NP)
    KEY[lane] = hull_i ? atan2f(PY[base + lane] - cy, PX[base + lane] - cx) : INFINITY;
  if (lane < 16) { VX[lane] = 0.f; VY[lane] = 0.f; }
  __syncthreads();
  if (lane < NP) {
    float ki = KEY[lane];
    int r = 0;
    #pragma unroll
    for (int j2 = 0; j2 < NP; j2++) {
      float kj = KEY[j2];
      r += (int)((kj < ki) || (kj == ki && j2 < lane));
    }
    VX[r] = PX[base + lane];
    VY[r] = PY[base + lane];
  }
  __syncthreads();
  return cnt;
}

// ============ k_post: per-block resolve + wave-parallel geometry + last-block final ============
__global__ void __launch_bounds__(64) k_post(const float* __restrict__ rpi,
                                             const float* __restrict__ rpr,
                                             const float* __restrict__ gob,
                                             const int* __restrict__ glab,
                                             const float* __restrict__ cls,
                                             int N, float* out, WS* ws) {
  __shared__ float PXs[16], PYs[16], VX[16], VY[16], DX[16], DY[16], KEY[16], RED[9];
  __shared__ int SJ[64];
  __shared__ unsigned long long SMK[64];
  int lane = threadIdx.x;
  int b = blockIdx.x;
  int a = b >> 6, p = b & 63;

  unsigned long long pk = ws->packed[a * 64 + lane];
  bool valid = (pk != ~0ULL);
  SJ[lane] = valid ? (int)(unsigned)(pk & 0xffffffffu) : (-1 - lane);
  SMK[lane] = (pk & 0xffffffff00000000ULL) | (unsigned)lane;  // (md, k) lexicographic
  __syncthreads();
  bool win = false;
  if (valid) {
    int j = SJ[lane];
    unsigned long long me = SMK[lane];
    win = true;
    for (int o = 0; o < 64; o++)
      if (SJ[o] == j && SMK[o] < me) win = false;
  }
  unsigned long long wmask = __ballot(win);
  int cnt = __popcll(wmask);
  if (p == 0 && lane == 0) atomicExch(&ws->cntpub[a], (unsigned)cnt);

  bool active = (p < cnt);
  if (active) {
    int kk = 0;
    { int c2 = 0;
      for (int o = 0; o < 64; o++)
        if ((wmask >> o) & 1ULL) { if (c2 == p) { kk = o; break; } c2++; } }
    int j = SJ[kk];
    const float* rep = (a ? rpr : rpi) + (size_t)j * 18;
    const float* gt8 = gob + (size_t)kk * 8;
    if (lane < 4) { PXs[lane] = gt8[2 * lane]; PYs[lane] = gt8[2 * lane + 1]; }
    else if (lane < 13) { int q = lane - 4; PXs[lane] = rep[2 * q]; PYs[lane] = rep[2 * q + 1]; }
    __syncthreads();

    float cenx = (((PXs[0] + PXs[1]) + PXs[2]) + PXs[3]) / 4.f;
    float ceny = (((PYs[0] + PYs[1]) + PYs[2]) + PYs[3]) / 4.f;
    float angv[4];
    int r4[4];
    #pragma unroll
    for (int i = 0; i < 4; i++) angv[i] = atan2f(PYs[i] - ceny, PXs[i] - cenx);
    #pragma unroll
    for (int i = 0; i < 4; i++) {
      int r = 0;
      #pragma unroll
      for (int j2 = 0; j2 < 4; j2++)
        r += (int)((angv[j2] < angv[i]) || (angv[j2] == angv[i] && j2 < i));
      r4[i] = r;
    }
    float qx[4], qy[4];
    #pragma unroll
    for (int d = 0; d < 4; d++) {
      float sx = 0.f, sy = 0.f;
      #pragma unroll
      for (int i = 0; i < 4; i++) if (r4[i] == d) { sx = PXs[i]; sy = PYs[i]; }
      qx[d] = sx; qy[d] = sy;
    }

    int cp = hull_wave<9>(PXs, PYs, 4, VX, VY, KEY, lane);
    float a_pred = shoe(VX, VY, cp);

    float sgt = 0.f;
    #pragma unroll
    for (int i = 0; i < 4; i++) {
      int nx = (i + 1) & 3;
      sgt += qx[i] * qy[nx] - qx[nx] * qy[i];
    }
    float a_gt = 0.5f * fabsf(sgt);

    int c = cp;
    c = clip_edge(VX, VY, DX, DY, c, qx[0], qy[0], qx[1], qy[1], lane);
    c = clip_edge(DX, DY, VX, VY, c, qx[1], qy[1], qx[2], qy[2], lane);
    c = clip_edge(VX, VY, DX, DY, c, qx[2], qy[2], qx[3], qy[3], lane);
    c = clip_edge(DX, DY, VX, VY, c, qx[3], qy[3], qx[0], qy[0], lane);
    float a_int = shoe(VX, VY, c);

    float uni = a_pred + a_gt - a_int;
    float iou = a_int / (uni + 1e-16f);

    int ch = hull_wave<13>(PXs, PYs, 0, VX, VY, KEY, lane);
    float a_hull = shoe(VX, VY, ch);
    float giou = iou - (a_hull - uni) / (a_hull + 1e-16f);
    float gl = 1.f - giou;

    float mxv = -INFINITY;
    if (lane < 36) {
      int pp = lane >> 2, e = lane & 3;
      float ax = e == 0 ? qx[0] : e == 1 ? qx[1] : e == 2 ? qx[2] : qx[3];
      float ay = e == 0 ? qy[0] : e == 1 ? qy[1] : e == 2 ? qy[2] : qy[3];
      float bx2 = e == 0 ? qx[1] : e == 1 ? qx[2] : e == 2 ? qx[3] : qx[0];
      float by2 = e == 0 ? qy[1] : e == 1 ? qy[2] : e == 2 ? qy[3] : qy[0];
      float ex = bx2 - ax, ey = by2 - ay;
      float nrm = sqrtf(ex * ex + ey * ey) + 1e-9f;
      float px = PXs[4 + pp], py = PYs[4 + pp];
      float s = (ex * (py - ay) - ey * (px - ax)) / nrm;
      mxv = -s;
    }
    float o1 = __shfl_xor(mxv, 1); mxv = fmaxf(mxv, o1);
    float o2 = __shfl_xor(mxv, 2); mxv = fmaxf(mxv, o2);
    if (lane < 36 && (lane & 3) == 0) RED[lane >> 2] = fmaxf(mxv, 0.f);
    __syncthreads();
    if (lane == 0) {
      float acc = 0.f;
      #pragma unroll
      for (int pp = 0; pp < 9; pp++) acc += RED[pp];
      float oob = acc / 9.f;
      atomicAdd(&ws->sums[1 + a * 2], (double)gl);
      atomicAdd(&ws->sums[2 + a * 2], (double)oob);
      if (a == 1) {
        int lab = glab[kk];
        double corr = (double)cls[(size_t)j * 16] - (double)cls[(size_t)j * 16 + lab];
        atomicAdd(&ws->sums[0], corr);
      }
    }
  }

  __syncthreads();
  if (lane == 0) {
    __threadfence();
    unsigned d = atomicAdd(&ws->done2, 1u);
    if (d == gridDim.x - 1) {
      __threadfence();
      double s0 = atomicAdd(&ws->sums[0], 0.0);
      double s1 = atomicAdd(&ws->sums[1], 0.0);
      double s2 = atomicAdd(&ws->sums[2], 0.0);
      double s3 = atomicAdd(&ws->sums[3], 0.0);
      double s4 = atomicAdd(&ws->sums[4], 0.0);
      unsigned c0 = atomicAdd(&ws->cntpub[0], 0u);
      unsigned c1 = atomicAdd(&ws->cntpub[1], 0u);
      double n0 = (double)(c0 > 1u ? c0 : 1u);
      double n1 = (double)(c1 > 1u ? c1 : 1u);
      out[0] = (float)(s0 / (double)N + 0.3 * (s1 / n0) + 1.0 * (s3 / n1) +
                       0.05 * (s2 / n0) + 0.1 * (s4 / n1));
    }
  }
}

extern "C" void kernel_launch(void* const* d_in, const int* in_sizes, int n_in,
                              void* d_out, int out_size, void* d_ws, size_t ws_size,
                              hipStream_t stream) {
  const float* rpi = (const float*)d_in[0];
  const float* rpr = (const float*)d_in[1];
  const float* cls = (const float*)d_in[2];
  const float* pstride = (const float*)d_in[3];
  const float* gob = (const float*)d_in[4];
  const int* glab = (const int*)d_in[5];
  int N = in_sizes[3];
  int K = in_sizes[5];
  if (K > 64) K = 64;
  WS* ws = (WS*)d_ws;

  int nb = (N + 255) / 256;
  k_init<<<1, 256, 0, stream>>>(ws);
  k_main<<<nb, 256, 0, stream>>>(rpi, rpr, cls, pstride, gob, N, K, ws);
  k_post<<<128, 64, 0, stream>>>(rpi, rpr, gob, glab, cls, N, (float*)d_out, ws);
}

// Round 7
// 104.532 us; speedup vs baseline: 1.1705x; 1.1705x over previous
//
#include <hip/hip_runtime.h>
#include <math.h>
#include <stdint.h>

// Match numpy float32 semantics exactly in branchy geometry (no FMA contraction).
#pragma clang fp contract(off)

#define SUB 16   // sub-blocks per (stage,gt) in argmin

struct WS {
  double sums[8];                  // 0 cls, 1 gl_i, 2 oob_i, 3 gl_r, 4 oob_r
  unsigned long long packed[128];  // (dd2_bits<<32)|idx per (a*64+k)
  unsigned cntpub[2];              // published positive counts
  unsigned done2;                  // k_post completion counter
};

// ============ k_init: zero accumulators (no global reads — replaces serial k_pre) ============
__global__ void k_init(WS* ws) {
  int t = threadIdx.x;
  if (t < 8) ws->sums[t] = 0.0;
  if (t < 128) ws->packed[t] = ~0ULL;
  if (t == 0) { ws->done2 = 0u; ws->cntpub[0] = 0u; ws->cntpub[1] = 0u; }
}

// ============ k_main: argmin blocks [0,AB) + cls blocks [AB, AB+nb) ============
// GT-centric (round-5 proven shape). Each argmin block redundantly computes its
// GT's prep + 2 level-bound binary searches (threads 0/1, L2-hot, TLP-hidden)
// — removes the serial 1-block k_pre and the per-point level check.
__global__ void __launch_bounds__(256) k_main(const float* __restrict__ rpi,
                                              const float* __restrict__ rpr,
                                              const float* __restrict__ cls,
                                              const float* __restrict__ stridev,
                                              const float* __restrict__ gob,
                                              int N, int K, int AB, WS* ws) {
  __shared__ unsigned long long sb[256];
  __shared__ float scx, scy, siw, sih;
  __shared__ int sbnd[2];
  int t = threadIdx.x;
  int b = blockIdx.x;
  if (b < AB) {
    int s = b % SUB;
    int ak = b / SUB;
    int a = ak / K;
    int k = ak % K;
    if (t < 2) {
      const float* g = gob + k * 8;
      float x0 = g[0], x1 = g[2], x2 = g[4], x3 = g[6];
      float y0 = g[1], y1 = g[3], y2 = g[5], y3 = g[7];
      float xmin = fminf(fminf(x0, x1), fminf(x2, x3));
      float xmax = fmaxf(fmaxf(x0, x1), fmaxf(x2, x3));
      float ymin = fminf(fminf(y0, y1), fminf(y2, y3));
      float ymax = fmaxf(fmaxf(y0, y1), fmaxf(y2, y3));
      float w = fmaxf(xmax - xmin, 1e-6f);
      float h = fmaxf(ymax - ymin, 1e-6f);
      int lmin = (int)log2f(stridev[0]);       // stridev sorted ascending by construction
      int lmax = (int)log2f(stridev[N - 1]);
      int gl = (int)((log2f(w * 0.25f) + log2f(h * 0.25f)) * 0.5f);  // trunc (positive)
      gl = gl < lmin ? lmin : (gl > lmax ? lmax : gl);
      // thread t searches lower_bound(2^(gl+t)): [lo,hi) of level gl
      float v = (float)(1 << (gl + t));
      int lo = 0, hi = N;
      while (lo < hi) { int mid = (lo + hi) >> 1; if (stridev[mid] < v) lo = mid + 1; else hi = mid; }
      sbnd[t] = lo;
      if (t == 0) {
        scx = (xmin + xmax) * 0.5f;
        scy = (ymin + ymax) * 0.5f;
        siw = 1.f / w; sih = 1.f / h;
      }
    }
    __syncthreads();
    int lo = sbnd[0], hi = sbnd[1];
    float cx = scx, cy = scy, iw = siw, ih = sih;
    const float* rep = a ? rpr : rpi;
    unsigned long long best = ~0ULL;
    for (int i = lo + s * 256 + t; i < hi; i += SUB * 256) {
      const float2 p = *(const float2*)(rep + (size_t)i * 18 + 8);
      float dx = (p.x - cx) * iw, dy = (p.y - cy) * ih;
      float d2 = dx * dx + dy * dy;  // d^2: monotone with d => identical winner set
      unsigned long long pk = ((unsigned long long)__float_as_uint(d2) << 32) | (unsigned)i;
      if (pk < best) best = pk;
    }
    sb[t] = best;
    __syncthreads();
    for (int off = 128; off > 0; off >>= 1) {
      if (t < off) { unsigned long long o = sb[t + off]; if (o < sb[t]) sb[t] = o; }
      __syncthreads();
    }
    if (t == 0 && sb[0] != ~0ULL) atomicMin(&ws->packed[a * 64 + k], sb[0]);
  } else {
    int i = (b - AB) * 256 + t;
    double v = 0.0;
    if (i < N) {
      const float4* r = (const float4*)(cls + (size_t)i * 16);
      float4 q0 = r[0], q1 = r[1], q2 = r[2], q3 = r[3];
      float x[16] = {q0.x, q0.y, q0.z, q0.w, q1.x, q1.y, q1.z, q1.w,
                     q2.x, q2.y, q2.z, q2.w, q3.x, q3.y, q3.z, q3.w};
      float m = x[0];
      for (int j = 1; j < 16; j++) m = fmaxf(m, x[j]);
      float ssum = 0.f;
      for (int j = 0; j < 16; j++) ssum += expf(x[j] - m);
      v = (double)(logf(ssum) + m - x[0]);
    }
    double* sd = (double*)sb;
    sd[t] = v;
    __syncthreads();
    for (int off = 128; off > 0; off >>= 1) {
      if (t < off) sd[t] += sd[t + off];
      __syncthreads();
    }
    if (t == 0) atomicAdd(&ws->sums[0], sd[0]);
  }
}

// ============ wave-parallel geometry helpers (block = 1 wave of 64) ============

__device__ __forceinline__ float shoe(const float* VX, const float* VY, int c) {
  float s = 0.f;
  #pragma unroll
  for (int i = 0; i < 16; i++) {
    if (i < c) {
      int nx = (i + 1 < c) ? ((i + 1 < 16) ? i + 1 : 15) : 0;  // JAX OOB-gather clamp
      s += VX[i] * VY[nx] - VX[nx] * VY[i];
    }
  }
  return 0.5f * fabsf(s);
}

__device__ __forceinline__ int clip_edge(const float* SX, const float* SY, float* DX, float* DY,
                                         int c, float ax, float ay, float bx, float by, int lane) {
  if (lane < 16) { DX[lane] = 0.f; DY[lane] = 0.f; }
  bool f_int = false, f_nxt = false;
  float ix = 0.f, iy = 0.f, nxv = 0.f, nyv = 0.f;
  if (lane < 16 && lane < c) {
    int nxt = (lane + 1 < c) ? lane + 1 : 0;
    if (nxt > 15) nxt = 15;
    float cxv = SX[lane], cyv = SY[lane];
    nxv = SX[nxt]; nyv = SY[nxt];
    float ex = bx - ax, ey = by - ay;
    float s_cur = ex * (cyv - ay) - ey * (cxv - ax);
    float s_nxt = ex * (nyv - ay) - ey * (nxv - ax);
    bool in_cur = s_cur >= 0.f, in_nxt = s_nxt >= 0.f;
    float den = s_cur - s_nxt;
    bool safe = fabsf(den) > 1e-9f;
    float tt = safe ? s_cur / den : 0.f;
    ix = cxv + tt * (nxv - cxv);
    iy = cyv + tt * (nyv - cyv);
    f_int = (in_cur != in_nxt);
    f_nxt = in_nxt;
  }
  unsigned long long bi = __ballot(f_int), bn = __ballot(f_nxt);
  unsigned long long lt = (1ULL << lane) - 1ULL;
  int below = __popcll(bi & lt) + __popcll(bn & lt);
  if (f_int && below < 16) { DX[below] = ix; DY[below] = iy; }
  int posn = below + (f_int ? 1 : 0);
  if (f_nxt && posn < 16) { DX[posn] = nxv; DY[posn] = nyv; }
  __syncthreads();
  return __popcll(bi) + __popcll(bn);
}

template <int NP>
__device__ __forceinline__ int hull_wave(const float* PX, const float* PY, int base,
                                         float* VX, float* VY, float* KEY, int lane) {
  constexpr int TOT = NP * NP;
  unsigned long long B0 = 0, B1 = 0, B2 = 0;
  {
    bool h = false;
    int idx = lane;
    if (idx < TOT) {
      int i = idx / NP, j = idx % NP;
      if (i != j) {
        float pix = PX[base + i], piy = PY[base + i];
        float dx = PX[base + j] - pix, dy = PY[base + j] - piy;
        float m = INFINITY;
        #pragma unroll
        for (int k = 0; k < NP; k++)
          m = fminf(m, dx * (PY[base + k] - piy) - dy * (PX[base + k] - pix));
        h = (m >= -1e-6f);
      }
    }
    B0 = __ballot(h);
  }
  if constexpr (TOT > 64) {
    bool h = false;
    int idx = lane + 64;
    if (idx < TOT) {
      int i = idx / NP, j = idx % NP;
      if (i != j) {
        float pix = PX[base + i], piy = PY[base + i];
        float dx = PX[base + j] - pix, dy = PY[base + j] - piy;
        float m = INFINITY;
        #pragma unroll
        for (int k = 0; k < NP; k++)
          m = fminf(m, dx * (PY[base + k] - piy) - dy * (PX[base + k] - pix));
        h = (m >= -1e-6f);
      }
    }
    B1 = __ballot(h);
  }
  if constexpr (TOT > 128) {
    bool h = false;
    int idx = lane + 128;
    if (idx < TOT) {
      int i = idx / NP, j = idx % NP;
      if (i != j) {
        float pix = PX[base + i], piy = PY[base + i];
        float dx = PX[base + j] - pix, dy = PY[base + j] - piy;
        float m = INFINITY;
        #pragma unroll
        for (int k = 0; k < NP; k++)
          m = fminf(m, dx * (PY[base + k] - piy) - dy * (PX[base + k] - pix));
        h = (m >= -1e-6f);
      }
    }
    B2 = __ballot(h);
  }
  bool hull_i = false;
  if (lane < NP) {
    int s = lane * NP, w = s >> 6, off = s & 63;
    unsigned long long Bw = (w == 0) ? B0 : ((w == 1) ? B1 : B2);
    unsigned long long Bw1 = (w == 0) ? B1 : ((w == 1) ? B2 : 0ULL);
    unsigned long long bits = Bw >> off;
    if (off) bits |= Bw1 << (64 - off);
    hull_i = (bits & ((1ULL << NP) - 1ULL)) != 0ULL;
  }
  unsigned long long hmask = __ballot(hull_i);
  int cnt = __popcll(hmask);
  float cx = 0.f, cy = 0.f;
  #pragma unroll
  for (int k = 0; k < NP; k++)
    if ((hmask >> k) & 1ULL) { cx += PX[base + k]; cy += PY[base + k]; }
  float dn = (float)(cnt > 1 ? cnt : 1);
  cx /= dn; cy /= dn;
  if (lane < NP)
    KEY[lane] = hull_i ? atan2f(PY[base + lane] - cy, PX[base + lane] - cx) : INFINITY;
  if (lane < 16) { VX[lane] = 0.f; VY[lane] = 0.f; }
  __syncthreads();
  if (lane < NP) {
    float ki = KEY[lane];
    int r = 0;
    #pragma unroll
    for (int j2 = 0; j2 < NP; j2++) {
      float kj = KEY[j2];
      r += (int)((kj < ki) || (kj == ki && j2 < lane));
    }
    VX[r] = PX[base + lane];
    VY[r] = PY[base + lane];
  }
  __syncthreads();
  return cnt;
}

// ============ k_post: per-block resolve + wave-parallel geometry + last-block final ============
__global__ void __launch_bounds__(64) k_post(const float* __restrict__ rpi,
                                             const float* __restrict__ rpr,
                                             const float* __restrict__ gob,
                                             const int* __restrict__ glab,
                                             const float* __restrict__ cls,
                                             int N, float* out, WS* ws) {
  __shared__ float PXs[16], PYs[16], VX[16], VY[16], DX[16], DY[16], KEY[16], RED[9];
  __shared__ int SJ[64];
  __shared__ unsigned long long SMK[64];
  int lane = threadIdx.x;
  int b = blockIdx.x;
  int a = b >> 6, p = b & 63;

  unsigned long long pk = ws->packed[a * 64 + lane];
  bool valid = (pk != ~0ULL);
  SJ[lane] = valid ? (int)(unsigned)(pk & 0xffffffffu) : (-1 - lane);
  SMK[lane] = (pk & 0xffffffff00000000ULL) | (unsigned)lane;  // (md, k) lexicographic
  __syncthreads();
  bool win = false;
  if (valid) {
    int j = SJ[lane];
    unsigned long long me = SMK[lane];
    win = true;
    for (int o = 0; o < 64; o++)
      if (SJ[o] == j && SMK[o] < me) win = false;
  }
  unsigned long long wmask = __ballot(win);
  int cnt = __popcll(wmask);
  if (p == 0 && lane == 0) atomicExch(&ws->cntpub[a], (unsigned)cnt);

  bool active = (p < cnt);
  if (active) {
    int kk = 0;
    { int c2 = 0;
      for (int o = 0; o < 64; o++)
        if ((wmask >> o) & 1ULL) { if (c2 == p) { kk = o; break; } c2++; } }
    int j = SJ[kk];
    const float* rep = (a ? rpr : rpi) + (size_t)j * 18;
    const float* gt8 = gob + (size_t)kk * 8;
    if (lane < 4) { PXs[lane] = gt8[2 * lane]; PYs[lane] = gt8[2 * lane + 1]; }
    else if (lane < 13) { int q = lane - 4; PXs[lane] = rep[2 * q]; PYs[lane] = rep[2 * q + 1]; }
    __syncthreads();

    float cenx = (((PXs[0] + PXs[1]) + PXs[2]) + PXs[3]) / 4.f;
    float ceny = (((PYs[0] + PYs[1]) + PYs[2]) + PYs[3]) / 4.f;
    float angv[4];
    int r4[4];
    #pragma unroll
    for (int i = 0; i < 4; i++) angv[i] = atan2f(PYs[i] - ceny, PXs[i] - cenx);
    #pragma unroll
    for (int i = 0; i < 4; i++) {
      int r = 0;
      #pragma unroll
      for (int j2 = 0; j2 < 4; j2++)
        r += (int)((angv[j2] < angv[i]) || (angv[j2] == angv[i] && j2 < i));
      r4[i] = r;
    }
    float qx[4], qy[4];
    #pragma unroll
    for (int d = 0; d < 4; d++) {
      float sx = 0.f, sy = 0.f;
      #pragma unroll
      for (int i = 0; i < 4; i++) if (r4[i] == d) { sx = PXs[i]; sy = PYs[i]; }
      qx[d] = sx; qy[d] = sy;
    }

    int cp = hull_wave<9>(PXs, PYs, 4, VX, VY, KEY, lane);
    float a_pred = shoe(VX, VY, cp);

    float sgt = 0.f;
    #pragma unroll
    for (int i = 0; i < 4; i++) {
      int nx = (i + 1) & 3;
      sgt += qx[i] * qy[nx] - qx[nx] * qy[i];
    }
    float a_gt = 0.5f * fabsf(sgt);

    int c = cp;
    c = clip_edge(VX, VY, DX, DY, c, qx[0], qy[0], qx[1], qy[1], lane);
    c = clip_edge(DX, DY, VX, VY, c, qx[1], qy[1], qx[2], qy[2], lane);
    c = clip_edge(VX, VY, DX, DY, c, qx[2], qy[2], qx[3], qy[3], lane);
    c = clip_edge(DX, DY, VX, VY, c, qx[3], qy[3], qx[0], qy[0], lane);
    float a_int = shoe(VX, VY, c);

    float uni = a_pred + a_gt - a_int;
    float iou = a_int / (uni + 1e-16f);

    int ch = hull_wave<13>(PXs, PYs, 0, VX, VY, KEY, lane);
    float a_hull = shoe(VX, VY, ch);
    float giou = iou - (a_hull - uni) / (a_hull + 1e-16f);
    float gl = 1.f - giou;

    float mxv = -INFINITY;
    if (lane < 36) {
      int pp = lane >> 2, e = lane & 3;
      float ax = e == 0 ? qx[0] : e == 1 ? qx[1] : e == 2 ? qx[2] : qx[3];
      float ay = e == 0 ? qy[0] : e == 1 ? qy[1] : e == 2 ? qy[2] : qy[3];
      float bx2 = e == 0 ? qx[1] : e == 1 ? qx[2] : e == 2 ? qx[3] : qx[0];
      float by2 = e == 0 ? qy[1] : e == 1 ? qy[2] : e == 2 ? qy[3] : qy[0];
      float ex = bx2 - ax, ey = by2 - ay;
      float nrm = sqrtf(ex * ex + ey * ey) + 1e-9f;
      float px = PXs[4 + pp], py = PYs[4 + pp];
      float s = (ex * (py - ay) - ey * (px - ax)) / nrm;
      mxv = -s;
    }
    float o1 = __shfl_xor(mxv, 1); mxv = fmaxf(mxv, o1);
    float o2 = __shfl_xor(mxv, 2); mxv = fmaxf(mxv, o2);
    if (lane < 36 && (lane & 3) == 0) RED[lane >> 2] = fmaxf(mxv, 0.f);
    __syncthreads();
    if (lane == 0) {
      float acc = 0.f;
      #pragma unroll
      for (int pp = 0; pp < 9; pp++) acc += RED[pp];
      float oob = acc / 9.f;
      atomicAdd(&ws->sums[1 + a * 2], (double)gl);
      atomicAdd(&ws->sums[2 + a * 2], (double)oob);
      if (a == 1) {
        int lab = glab[kk];
        double corr = (double)cls[(size_t)j * 16] - (double)cls[(size_t)j * 16 + lab];
        atomicAdd(&ws->sums[0], corr);
      }
    }
  }

  __syncthreads();
  if (lane == 0) {
    __threadfence();
    unsigned d = atomicAdd(&ws->done2, 1u);
    if (d == gridDim.x - 1) {
      __threadfence();
      double s0 = atomicAdd(&ws->sums[0], 0.0);
      double s1 = atomicAdd(&ws->sums[1], 0.0);
      double s2 = atomicAdd(&ws->sums[2], 0.0);
      double s3 = atomicAdd(&ws->sums[3], 0.0);
      double s4 = atomicAdd(&ws->sums[4], 0.0);
      unsigned c0 = atomicAdd(&ws->cntpub[0], 0u);
      unsigned c1 = atomicAdd(&ws->cntpub[1], 0u);
      double n0 = (double)(c0 > 1u ? c0 : 1u);
      double n1 = (double)(c1 > 1u ? c1 : 1u);
      out[0] = (float)(s0 / (double)N + 0.3 * (s1 / n0) + 1.0 * (s3 / n1) +
                       0.05 * (s2 / n0) + 0.1 * (s4 / n1));
    }
  }
}

extern "C" void kernel_launch(void* const* d_in, const int* in_sizes, int n_in,
                              void* d_out, int out_size, void* d_ws, size_t ws_size,
                              hipStream_t stream) {
  const float* rpi = (const float*)d_in[0];
  const float* rpr = (const float*)d_in[1];
  const float* cls = (const float*)d_in[2];
  const float* pstride = (const float*)d_in[3];
  const float* gob = (const float*)d_in[4];
  const int* glab = (const int*)d_in[5];
  int N = in_sizes[3];
  int K = in_sizes[5];
  if (K > 64) K = 64;
  WS* ws = (WS*)d_ws;

  int AB = 2 * K * SUB;
  int nb = (N + 255) / 256;
  k_init<<<1, 256, 0, stream>>>(ws);
  k_main<<<AB + nb, 256, 0, stream>>>(rpi, rpr, cls, pstride, gob, N, K, AB, ws);
  k_post<<<128, 64, 0, stream>>>(rpi, rpr, gob, glab, cls, N, (float*)d_out, ws);
}